// Round 3
// baseline (236.117 us; speedup 1.0000x reference)
//
#include <hip/hip_runtime.h>

typedef __attribute__((ext_vector_type(8))) __bf16 bf16x8;
typedef __attribute__((ext_vector_type(4))) float f32x4;
typedef unsigned short u16;
typedef unsigned int u32;

#define MFMA16(a, b, c) __builtin_amdgcn_mfma_f32_16x16x32_bf16((a), (b), (c), 0, 0, 0)

__device__ __forceinline__ u16 f2bf(float f) {
  return (u16)((__float_as_uint(f) + 0x8000u) >> 16);
}

// dims
#define BDIM 2
#define SDIM 2048
#define EDIM 1024
#define HDIM 16
#define HD 64
#define MDIM (BDIM * SDIM)  // 4096

// q pre-scale: 0.125 * log2(e), folded into q at the QKV-GEMM epilogue
#define SC_C1 0.1803368801111355f

typedef __attribute__((address_space(3))) void lds_void;
typedef __attribute__((address_space(1))) void g_void;

__device__ __forceinline__ void async_lds16(const void* g, void* lds_byte) {
  __builtin_amdgcn_global_load_lds((const g_void*)g, (lds_void*)lds_byte, 16, 0, 0);
}

// ===================== cvt3: three f32 -> bf16 arrays, one launch ==========
__global__ __launch_bounds__(256) void cvt3_kernel(
    const float* __restrict__ s0, u16* __restrict__ d0, int n0,
    const float* __restrict__ s1, u16* __restrict__ d1, int n1,
    const float* __restrict__ s2, u16* __restrict__ d2, int n2) {
  int i = (blockIdx.x * 256 + threadIdx.x) * 8;
  const float* s;
  u16* d;
  if (i < n0) {
    s = s0 + i; d = d0 + i;
  } else if (i < n0 + n1) {
    s = s1 + (i - n0); d = d1 + (i - n0);
  } else if (i < n0 + n1 + n2) {
    s = s2 + (i - n0 - n1); d = d2 + (i - n0 - n1);
  } else {
    return;
  }
  float4 f0 = *(const float4*)(s);
  float4 f1 = *(const float4*)(s + 4);
  union { uint4 u; u16 h[8]; } o;
  o.h[0] = f2bf(f0.x); o.h[1] = f2bf(f0.y); o.h[2] = f2bf(f0.z); o.h[3] = f2bf(f0.w);
  o.h[4] = f2bf(f1.x); o.h[5] = f2bf(f1.y); o.h[6] = f2bf(f1.z); o.h[7] = f2bf(f1.w);
  *(uint4*)(d) = o.u;
}

// ===================== GEMM1: QKV projection (128x128 tile, BK=64) ====
// out: q bf16 [B][H][S][HD] PRE-SCALED by SC_C1; k bf16 [B][H][S][HD];
//      v bf16 TRANSPOSED [B][H][HD][S]
__global__ __launch_bounds__(256) void gemm_qkv_kernel(
    const u16* __restrict__ X, const u16* __restrict__ W,
    const float* __restrict__ bias, u16* __restrict__ qb,
    u16* __restrict__ kb, u16* __restrict__ vtb) {
  __shared__ __align__(16) u16 As[128 * 64];
  __shared__ __align__(16) u16 Bs[128 * 64];
  const int m0 = blockIdx.x * 128, n0 = blockIdx.y * 128;
  const bool isV = (n0 >= 2 * EDIM);
  const int t = threadIdx.x;
  const int l = t & 63;
  const int quad = l >> 4, col = l & 15;
  const int wid = t >> 6;
  const int mh = wid & 1, nh = wid >> 1;
  const int wofs = (t & 192) << 4;  // wave_id * 1024 bytes
  f32x4 acc[4][4] = {};
  const u16* Ab = X + (size_t)m0 * EDIM;
  const u16* Bb = W + (size_t)n0 * EDIM;
  char* AsB = (char*)As;
  char* BsB = (char*)Bs;

  for (int k0 = 0; k0 < EDIM; k0 += 64) {
    __syncthreads();
#pragma unroll
    for (int p = 0; p < 4; p++) {
      int idx = p * 256 + t;       // 0..1023
      int row = idx >> 3;          // 0..127
      int gch = (idx & 7) ^ (row & 7);
      async_lds16(Ab + (size_t)row * EDIM + k0 + gch * 8, AsB + p * 4096 + wofs);
      async_lds16(Bb + (size_t)row * EDIM + k0 + gch * 8, BsB + p * 4096 + wofs);
    }
    __syncthreads();
#pragma unroll
    for (int kk = 0; kk < 2; kk++) {
      bf16x8 af[4], bfr[4];
#pragma unroll
      for (int i = 0; i < 4; i++) {
        int ra = 64 * mh + 16 * i + col;
        af[i] = *(const bf16x8*)&As[ra * 64 + (((kk * 4 + quad) ^ (ra & 7)) * 8)];
        int rb = 64 * nh + 16 * i + col;
        bfr[i] = *(const bf16x8*)&Bs[rb * 64 + (((kk * 4 + quad) ^ (rb & 7)) * 8)];
      }
      if (isV) {
#pragma unroll
        for (int i = 0; i < 4; i++)
#pragma unroll
          for (int j = 0; j < 4; j++)
            acc[i][j] = MFMA16(bfr[i], af[j], acc[i][j]);  // rows = W features
      } else {
#pragma unroll
        for (int i = 0; i < 4; i++)
#pragma unroll
          for (int j = 0; j < 4; j++)
            acc[i][j] = MFMA16(af[i], bfr[j], acc[i][j]);  // rows = tokens
      }
    }
  }

  if (isV) {
#pragma unroll
    for (int i = 0; i < 4; i++)
#pragma unroll
      for (int j = 0; j < 4; j++)
#pragma unroll
        for (int r = 0; r < 4; r++) {
          int n = n0 + 64 * nh + 16 * i + quad * 4 + r;  // feature (2048..3071)
          int m = m0 + 64 * mh + 16 * j + col;           // token
          float val = acc[i][j][r] + bias[n];
          int e = n & 1023;
          int hh = e >> 6, d = e & 63;
          int bb = m >> 11, s = m & 2047;
          vtb[(((size_t)(bb * HDIM + hh)) * HD + d) * SDIM + s] = f2bf(val);
        }
  } else {
    const float qscale = (n0 < EDIM) ? SC_C1 : 1.0f;  // block-uniform
#pragma unroll
    for (int i = 0; i < 4; i++)
#pragma unroll
      for (int j = 0; j < 4; j++)
#pragma unroll
        for (int r = 0; r < 4; r++) {
          int m = m0 + 64 * mh + 16 * i + quad * 4 + r;
          int n = n0 + 64 * nh + 16 * j + col;
          float val = (acc[i][j][r] + bias[n]) * qscale;
          int which = n >> 10, e = n & 1023;
          int hh = e >> 6, d = e & 63;
          int bb = m >> 11, s = m & 2047;
          u16* dst = (which == 0) ? qb : kb;
          dst[(((size_t)(bb * HDIM + hh)) * SDIM + s) * HD + d] = f2bf(val);
        }
  }
}

// ===================== Attention: counted-vmcnt flash pipeline ============
// T3/T4: K,V triple-buffered; per iter {s_waitcnt vmcnt(4); s_barrier;
// stage(t+2); QK^T(t) -> softmax(t) -> PV(t)}. vmcnt never drains to 0 in
// the main loop: stage(t) is issued 2 full phases before its wait.
// SWAPPED QK^T (mfma(K,Q)): lane holds one q (col) x 16 k (quad*4+r per ct).
// ROUND-2 BUG FIXED: kf(half) must pair with aq(half) only — round 2
// multiplied each kf by BOTH Q halves (cross terms K0.Q1+K1.Q0 -> absmax 3.6e-2).
// Ps layout: row stride 128 B; 16B chunk c at phys (c ^ (row&7)), 8B halves
// swapped by row bit 3 -> b64 writes AND b64 reads are bank-conflict-free.
// LDS = 3*8K + 3*8K + 8K = 57344 B -> 2 blocks/CU (= measured occupancy).
__global__ __launch_bounds__(256) void attn_kernel(
    const u16* __restrict__ qg, const u16* __restrict__ kg,
    const u16* __restrict__ vtg, u16* __restrict__ ctx) {
  __shared__ __align__(16) u16 KB[3][64 * 64];
  __shared__ __align__(16) u16 VB[3][64 * 64];
  __shared__ __align__(16) u16 Ps[64 * 64];

  const int bh = blockIdx.x;  // b*16 + h
  const int q0 = blockIdx.y * 64;
  const int t = threadIdx.x;
  const int wid = t >> 6, l = t & 63;
  const int quad = l >> 4, col = l & 15;
  const size_t base = (size_t)bh * SDIM * HD;

  // Q fragments (B-operand under swapped QK^T): lane col -> q row q0+16*wid+col
  bf16x8 aq0, aq1;
  {
    const u16* qp = qg + base + (size_t)(q0 + 16 * wid + col) * HD + quad * 8;
    aq0 = *(const bf16x8*)(qp);
    aq1 = *(const bf16x8*)(qp + 32);
  }
  // Force Q-load completion NOW, before the async stages are issued, so the
  // compiler's wait for aq cannot land inside the loop and drain the pipe.
  asm volatile("" : "+v"(aq0), "+v"(aq1));

  const int qi = q0 + 16 * wid + col;         // this lane's q row (mask/psum)
  const int qrow = q0 + 16 * wid + quad * 4;  // + r (oacc rows)

  // staging: row = (t>>3), chunk g = (t&7)^(row&7)
  const int srow = t >> 3;
  const int g = (t & 7) ^ (srow & 7);
  const u16* kptr = kg + base + (size_t)srow * HD + g * 8;
  const u16* vptr = vtg + base + (size_t)srow * SDIM + g * 8;
  const int wofs = (t & 192) << 4;

  auto stageK = [&](int kt, int buf) {
    char* d = (char*)KB[buf] + wofs;
    async_lds16(kptr + (size_t)(kt * 64) * HD, d);
    async_lds16(kptr + (size_t)(kt * 64 + 32) * HD, d + 4096);
  };
  auto stageV = [&](int kt, int buf) {
    char* d = (char*)VB[buf] + wofs;
    async_lds16(vptr + kt * 64, d);
    async_lds16(vptr + (size_t)32 * SDIM + kt * 64, d + 4096);
  };

  // swapped QK^T: A = K rows (k index), B = Q (col = q).
  // C: row = k-sub (quad*4+r), col = q-local (lane&15).
  // kf(half) covers K head-dims [32*half,32*half+32) -> pairs with aq(half).
  auto qkt = [&](const u16* Kt, f32x4* sco) {
#pragma unroll
    for (int half = 0; half < 2; half++) {
      bf16x8 aqh = half ? aq1 : aq0;
#pragma unroll
      for (int ct = 0; ct < 4; ct++) {
        int r = 16 * ct + col;
        int phys = (4 * half + quad) ^ (r & 7);
        bf16x8 kf = *(const bf16x8*)&Kt[r * 64 + phys * 8];
        sco[ct] = MFMA16(kf, aqh, sco[ct]);
      }
    }
  };

  // --- Ps addressing: 4-bit swizzle (chunk XOR row&7, 8B-half XOR row>>3) ---
  char* PsB = (char*)Ps;
  const int prow = 16 * wid + col;     // Ps row = q-local; row&15 == col
  const int sub0 = (col >> 3) << 3;    // 0 or 8: phys offset of logical half 0
  int wPs[4], rLo[2], rHi[2];
#pragma unroll
  for (int ct = 0; ct < 4; ct++)
    wPs[ct] = prow * 128 + (((2 * ct + (quad >> 1)) ^ (col & 7)) << 4) +
              (((quad & 1) << 3) ^ sub0);
#pragma unroll
  for (int half = 0; half < 2; half++) {
    int cb = prow * 128 + (((4 * half + quad) ^ (col & 7)) << 4);
    rLo[half] = cb + sub0;        // logical k-lo 4
    rHi[half] = cb + (8 - sub0);  // logical k-hi 4
  }

  float psum = 0.f;
  f32x4 oacc[4] = {};

  // softmax(t): per lane 16 scores for q=qi, k = kt*64 + 16*ct + quad*4 + r.
  auto smax = [&](int kt, f32x4 (&cur)[4], bool band) {
#pragma unroll
    for (int ct = 0; ct < 4; ct++) {
      float p[4];
#pragma unroll
      for (int r = 0; r < 4; r++) {
        float s = cur[ct][r];
        if (band) {
          int j = kt * 64 + 16 * ct + quad * 4 + r;
          if (j <= qi && j + 16 >= qi) s = -1.0e30f;
        }
        p[r] = __builtin_exp2f(s);
        psum += p[r];
      }
      u32 w0, w1;
      asm("v_cvt_pk_bf16_f32 %0, %1, %2" : "=v"(w0) : "v"(p[0]), "v"(p[1]));
      asm("v_cvt_pk_bf16_f32 %0, %1, %2" : "=v"(w1) : "v"(p[2]), "v"(p[3]));
      uint2 w;
      w.x = w0;
      w.y = w1;
      *(uint2*)(PsB + wPs[ct]) = w;
    }
  };

  auto pv = [&](const u16* Vt) {
#pragma unroll
    for (int half = 0; half < 2; half++) {
      uint2 lo = *(const uint2*)(PsB + rLo[half]);
      uint2 hi = *(const uint2*)(PsB + rHi[half]);
      uint4 pw;
      pw.x = lo.x; pw.y = lo.y; pw.z = hi.x; pw.w = hi.y;
      bf16x8 pa = __builtin_bit_cast(bf16x8, pw);
#pragma unroll
      for (int dt = 0; dt < 4; dt++) {
        int vr = 16 * dt + col;
        int phys = (4 * half + quad) ^ (vr & 7);
        bf16x8 vf = *(const bf16x8*)&Vt[vr * 64 + phys * 8];
        oacc[dt] = MFMA16(pa, vf, oacc[dt]);
      }
    }
  };

  const int NT = SDIM / 64;  // 32

  // prologue: 2 tiles in flight
  stageK(0, 0);
  stageV(0, 0);
  stageK(1, 1);
  stageV(1, 1);

  int cur = 0, stg = 2;
#pragma unroll 1
  for (int kt = 0; kt < NT; ++kt) {
    if (kt < NT - 1) {
      asm volatile("s_waitcnt vmcnt(4)" ::: "memory");  // stage(kt) landed
    } else {
      asm volatile("s_waitcnt vmcnt(0)" ::: "memory");
    }
    __builtin_amdgcn_s_barrier();  // all waves' stage(kt) landed
    if (kt + 2 < NT) {             // buf stg last read in iter kt-1: safe
      stageK(kt + 2, stg);
      stageV(kt + 2, stg);
    }
    f32x4 sc[4] = {};
    __builtin_amdgcn_s_setprio(1);
    qkt(KB[cur], sc);
    __builtin_amdgcn_s_setprio(0);
    bool band = (kt * 64 <= q0 + 63) && (kt * 64 + 63 >= q0 - 16);
    smax(kt, sc, band);
    __builtin_amdgcn_s_setprio(1);
    pv(VB[cur]);
    __builtin_amdgcn_s_setprio(0);
    cur = (cur == 2) ? 0 : cur + 1;
    stg = (stg == 2) ? 0 : stg + 1;
  }

  // reduce l across quads (k is lane-local; quads hold disjoint k subsets)
  psum += __shfl_xor(psum, 16, 64);
  psum += __shfl_xor(psum, 32, 64);

  // epilogue: ctx[b][s][h*64+d] = O / l   (bf16)
  const int b = bh >> 4, h = bh & 15;
  float linv[4];
#pragma unroll
  for (int r = 0; r < 4; r++)
    linv[r] = 1.0f / __shfl(psum, quad * 4 + r, 64);
#pragma unroll
  for (int dt = 0; dt < 4; dt++)
#pragma unroll
    for (int r = 0; r < 4; r++) {
      int qgl = qrow + r;
      int d = 16 * dt + col;
      ctx[((size_t)(b * SDIM + qgl)) * EDIM + h * HD + d] =
          f2bf(oacc[dt][r] * linv[r]);
    }
}

// ===================== GEMM2: output projection (128x128 tile, BK=64) ======
__global__ __launch_bounds__(256) void gemm_out_kernel(
    const u16* __restrict__ A, const u16* __restrict__ W,
    const float* __restrict__ bias, float* __restrict__ out) {
  __shared__ __align__(16) u16 As[128 * 64];
  __shared__ __align__(16) u16 Bs[128 * 64];
  const int m0 = blockIdx.x * 128, n0 = blockIdx.y * 128;
  const int t = threadIdx.x;
  const int l = t & 63;
  const int quad = l >> 4, col = l & 15;
  const int wid = t >> 6;
  const int mh = wid & 1, nh = wid >> 1;
  const int wofs = (t & 192) << 4;
  f32x4 acc[4][4] = {};
  const u16* Ab = A + (size_t)m0 * EDIM;
  const u16* Bb = W + (size_t)n0 * EDIM;
  char* AsB = (char*)As;
  char* BsB = (char*)Bs;

  for (int k0 = 0; k0 < EDIM; k0 += 64) {
    __syncthreads();
#pragma unroll
    for (int p = 0; p < 4; p++) {
      int idx = p * 256 + t;
      int row = idx >> 3;
      int gch = (idx & 7) ^ (row & 7);
      async_lds16(Ab + (size_t)row * EDIM + k0 + gch * 8, AsB + p * 4096 + wofs);
      async_lds16(Bb + (size_t)row * EDIM + k0 + gch * 8, BsB + p * 4096 + wofs);
    }
    __syncthreads();
#pragma unroll
    for (int kk = 0; kk < 2; kk++) {
      bf16x8 af[4], bfr[4];
#pragma unroll
      for (int i = 0; i < 4; i++) {
        int ra = 64 * mh + 16 * i + col;
        af[i] = *(const bf16x8*)&As[ra * 64 + (((kk * 4 + quad) ^ (ra & 7)) * 8)];
        int rb = 64 * nh + 16 * i + col;
        bfr[i] = *(const bf16x8*)&Bs[rb * 64 + (((kk * 4 + quad) ^ (rb & 7)) * 8)];
      }
#pragma unroll
      for (int i = 0; i < 4; i++)
#pragma unroll
        for (int j = 0; j < 4; j++)
          acc[i][j] = MFMA16(af[i], bfr[j], acc[i][j]);
    }
  }

#pragma unroll
  for (int i = 0; i < 4; i++)
#pragma unroll
    for (int j = 0; j < 4; j++)
#pragma unroll
      for (int r = 0; r < 4; r++) {
        int m = m0 + 64 * mh + 16 * i + quad * 4 + r;
        int n = n0 + 64 * nh + 16 * j + col;
        out[(size_t)m * EDIM + n] = acc[i][j][r] + bias[n];
      }
}

extern "C" void kernel_launch(void* const* d_in, const int* in_sizes, int n_in,
                              void* d_out, int out_size, void* d_ws,
                              size_t ws_size, hipStream_t stream) {
  const float* x = (const float*)d_in[0];
  const float* in_w = (const float*)d_in[2];
  const float* in_b = (const float*)d_in[3];
  const float* out_w = (const float*)d_in[4];
  const float* out_b = (const float*)d_in[5];
  float* out = (float*)d_out;

  char* ws = (char*)d_ws;
  u16* Xb  = (u16*)ws;                           // 8 MB (reused as ctx)
  u16* ctx = (u16*)ws;                           // alias of Xb
  u16* qb  = (u16*)(ws + (size_t)( 8 << 20));    // 8 MB (pre-scaled q)
  u16* kb  = (u16*)(ws + (size_t)(16 << 20));    // 8 MB
  u16* vtb = (u16*)(ws + (size_t)(24 << 20));    // 8 MB (transposed V)
  u16* Wib = (u16*)(ws + (size_t)(32 << 20));    // 6 MB
  u16* Wob = (u16*)(ws + (size_t)(38 << 20));    // 2 MB

  const int nX = MDIM * EDIM;
  const int nWi = 3 * EDIM * EDIM;
  const int nWo = EDIM * EDIM;
  cvt3_kernel<<<(nX + nWi + nWo) / 8 / 256, 256, 0, stream>>>(
      x, Xb, nX, in_w, Wib, nWi, out_w, Wob, nWo);

  gemm_qkv_kernel<<<dim3(MDIM / 128, 3 * EDIM / 128), 256, 0, stream>>>(
      Xb, Wib, in_b, qb, kb, vtb);
  attn_kernel<<<dim3(BDIM * HDIM, SDIM / 64), 256, 0, stream>>>(qb, kb, vtb, ctx);
  gemm_out_kernel<<<dim3(MDIM / 128, EDIM / 128), 256, 0, stream>>>(
      ctx, Wob, out_b, out);
}

// Round 4
// 219.747 us; speedup vs baseline: 1.0745x; 1.0745x over previous
//
#include <hip/hip_runtime.h>

typedef __attribute__((ext_vector_type(8))) __bf16 bf16x8;
typedef __attribute__((ext_vector_type(4))) float f32x4;
typedef __attribute__((ext_vector_type(16))) float f32x16;
typedef unsigned short u16;
typedef unsigned int u32;

#define MFMA16(a, b, c) __builtin_amdgcn_mfma_f32_16x16x32_bf16((a), (b), (c), 0, 0, 0)
#define MFMA32(a, b, c) __builtin_amdgcn_mfma_f32_32x32x16_bf16((a), (b), (c), 0, 0, 0)

__device__ __forceinline__ u16 f2bf(float f) {
  return (u16)((__float_as_uint(f) + 0x8000u) >> 16);
}

// dims
#define BDIM 2
#define SDIM 2048
#define EDIM 1024
#define HDIM 16
#define HD 64
#define MDIM (BDIM * SDIM)  // 4096

// q pre-scale: 0.125 * log2(e), folded into q at the QKV-GEMM epilogue
#define SC_C1 0.1803368801111355f

typedef __attribute__((address_space(3))) void lds_void;
typedef __attribute__((address_space(1))) void g_void;

__device__ __forceinline__ void async_lds16(const void* g, void* lds_byte) {
  __builtin_amdgcn_global_load_lds((const g_void*)g, (lds_void*)lds_byte, 16, 0, 0);
}

// ===================== cvt3: three f32 -> bf16 arrays, one launch ==========
__global__ __launch_bounds__(256) void cvt3_kernel(
    const float* __restrict__ s0, u16* __restrict__ d0, int n0,
    const float* __restrict__ s1, u16* __restrict__ d1, int n1,
    const float* __restrict__ s2, u16* __restrict__ d2, int n2) {
  int i = (blockIdx.x * 256 + threadIdx.x) * 8;
  const float* s;
  u16* d;
  if (i < n0) {
    s = s0 + i; d = d0 + i;
  } else if (i < n0 + n1) {
    s = s1 + (i - n0); d = d1 + (i - n0);
  } else if (i < n0 + n1 + n2) {
    s = s2 + (i - n0 - n1); d = d2 + (i - n0 - n1);
  } else {
    return;
  }
  float4 f0 = *(const float4*)(s);
  float4 f1 = *(const float4*)(s + 4);
  union { uint4 u; u16 h[8]; } o;
  o.h[0] = f2bf(f0.x); o.h[1] = f2bf(f0.y); o.h[2] = f2bf(f0.z); o.h[3] = f2bf(f0.w);
  o.h[4] = f2bf(f1.x); o.h[5] = f2bf(f1.y); o.h[6] = f2bf(f1.z); o.h[7] = f2bf(f1.w);
  *(uint4*)(d) = o.u;
}

// ===================== GEMM1: QKV projection (128x128 tile, BK=64) ====
// out: q bf16 [B][H][S][HD] PRE-SCALED by SC_C1; k bf16 [B][H][S][HD];
//      v bf16 TRANSPOSED [B][H][HD][S]
__global__ __launch_bounds__(256) void gemm_qkv_kernel(
    const u16* __restrict__ X, const u16* __restrict__ W,
    const float* __restrict__ bias, u16* __restrict__ qb,
    u16* __restrict__ kb, u16* __restrict__ vtb) {
  __shared__ __align__(16) u16 As[128 * 64];
  __shared__ __align__(16) u16 Bs[128 * 64];
  const int m0 = blockIdx.x * 128, n0 = blockIdx.y * 128;
  const bool isV = (n0 >= 2 * EDIM);
  const int t = threadIdx.x;
  const int l = t & 63;
  const int quad = l >> 4, col = l & 15;
  const int wid = t >> 6;
  const int mh = wid & 1, nh = wid >> 1;
  const int wofs = (t & 192) << 4;  // wave_id * 1024 bytes
  f32x4 acc[4][4] = {};
  const u16* Ab = X + (size_t)m0 * EDIM;
  const u16* Bb = W + (size_t)n0 * EDIM;
  char* AsB = (char*)As;
  char* BsB = (char*)Bs;

  for (int k0 = 0; k0 < EDIM; k0 += 64) {
    __syncthreads();
#pragma unroll
    for (int p = 0; p < 4; p++) {
      int idx = p * 256 + t;       // 0..1023
      int row = idx >> 3;          // 0..127
      int gch = (idx & 7) ^ (row & 7);
      async_lds16(Ab + (size_t)row * EDIM + k0 + gch * 8, AsB + p * 4096 + wofs);
      async_lds16(Bb + (size_t)row * EDIM + k0 + gch * 8, BsB + p * 4096 + wofs);
    }
    __syncthreads();
#pragma unroll
    for (int kk = 0; kk < 2; kk++) {
      bf16x8 af[4], bfr[4];
#pragma unroll
      for (int i = 0; i < 4; i++) {
        int ra = 64 * mh + 16 * i + col;
        af[i] = *(const bf16x8*)&As[ra * 64 + (((kk * 4 + quad) ^ (ra & 7)) * 8)];
        int rb = 64 * nh + 16 * i + col;
        bfr[i] = *(const bf16x8*)&Bs[rb * 64 + (((kk * 4 + quad) ^ (rb & 7)) * 8)];
      }
      if (isV) {
#pragma unroll
        for (int i = 0; i < 4; i++)
#pragma unroll
          for (int j = 0; j < 4; j++)
            acc[i][j] = MFMA16(bfr[i], af[j], acc[i][j]);  // rows = W features
      } else {
#pragma unroll
        for (int i = 0; i < 4; i++)
#pragma unroll
          for (int j = 0; j < 4; j++)
            acc[i][j] = MFMA16(af[i], bfr[j], acc[i][j]);  // rows = tokens
      }
    }
  }

  if (isV) {
#pragma unroll
    for (int i = 0; i < 4; i++)
#pragma unroll
      for (int j = 0; j < 4; j++)
#pragma unroll
        for (int r = 0; r < 4; r++) {
          int n = n0 + 64 * nh + 16 * i + quad * 4 + r;  // feature (2048..3071)
          int m = m0 + 64 * mh + 16 * j + col;           // token
          float val = acc[i][j][r] + bias[n];
          int e = n & 1023;
          int hh = e >> 6, d = e & 63;
          int bb = m >> 11, s = m & 2047;
          vtb[(((size_t)(bb * HDIM + hh)) * HD + d) * SDIM + s] = f2bf(val);
        }
  } else {
    const float qscale = (n0 < EDIM) ? SC_C1 : 1.0f;  // block-uniform
#pragma unroll
    for (int i = 0; i < 4; i++)
#pragma unroll
      for (int j = 0; j < 4; j++)
#pragma unroll
        for (int r = 0; r < 4; r++) {
          int m = m0 + 64 * mh + 16 * i + quad * 4 + r;
          int n = n0 + 64 * nh + 16 * j + col;
          float val = (acc[i][j][r] + bias[n]) * qscale;
          int which = n >> 10, e = n & 1023;
          int hh = e >> 6, d = e & 63;
          int bb = m >> 11, s = m & 2047;
          u16* dst = (which == 0) ? qb : kb;
          dst[(((size_t)(bb * HDIM + hh)) * SDIM + s) * HD + d] = f2bf(val);
        }
  }
}

// ===================== Attention: 32x32 swapped QK^T, in-register softmax ==
// QK^T = mfma(K, Q) 32x32x16: lane holds P[k][q=lane&31] for 32 k values:
// k = 32*s + (reg&3) + 8*(reg>>2) + 4*(lane>>5)  (C layout, m74/m101).
// Softmax entirely in registers; P->bf16 via 16 cvt_pk + 8 permlane32_swap
// builds PV B-fragments directly (NO Ps LDS round-trip).
// PV = mfma(V^T, P) -> O as D[d][q]; epilogue packs 8B stores.
// Schedule = round-0 proven overlap: barrier; QK^T(t+1) [MFMA bg];
// stage(t+2); smax(t) [VALU overlaps]; PV(t). K dbuf x2, V x3.
// Each wave owns 32 q -> QBLK=128/block, grid 32x16=512 blocks (2/CU).
// LDS = 2*8K + 3*8K = 40960 B.
__global__ __launch_bounds__(256) void attn_kernel(
    const u16* __restrict__ qg, const u16* __restrict__ kg,
    const u16* __restrict__ vtg, u16* __restrict__ ctx) {
  __shared__ __align__(16) u16 KB[2][64 * 64];
  __shared__ __align__(16) u16 VB[3][64 * 64];

  const int bh = blockIdx.x;  // b*16 + h
  const int q0 = blockIdx.y * 128;
  const int t = threadIdx.x;
  const int wid = t >> 6, l = t & 63;
  const int col = l & 31, half = l >> 5;
  const size_t base = (size_t)bh * SDIM * HD;

  const int qw0 = q0 + 32 * wid;   // wave's first q row
  const int qi = qw0 + col;        // this lane's q row

  // Q B-fragments (32x32x16): lane holds Q[q=col][d = 16*f + 8*half + e]
  bf16x8 bq[4];
  {
    const u16* qp = qg + base + (size_t)qi * HD + half * 8;
#pragma unroll
    for (int f = 0; f < 4; f++) bq[f] = *(const bf16x8*)(qp + f * 16);
  }
  asm volatile("" : "+v"(bq[0]), "+v"(bq[1]), "+v"(bq[2]), "+v"(bq[3]));

  // staging: row = (t>>3), chunk g = (t&7)^(row&7)  (verified r0-r3)
  const int srow = t >> 3;
  const int g = (t & 7) ^ (srow & 7);
  const u16* kptr = kg + base + (size_t)srow * HD + g * 8;
  const u16* vptr = vtg + base + (size_t)srow * SDIM + g * 8;
  const int wofs = (t & 192) << 4;

  auto stageK = [&](int kt, int buf) {
    char* d = (char*)KB[buf] + wofs;
    async_lds16(kptr + (size_t)(kt * 64) * HD, d);
    async_lds16(kptr + (size_t)(kt * 64 + 32) * HD, d + 4096);
  };
  auto stageV = [&](int kt, int buf) {
    char* d = (char*)VB[buf] + wofs;
    async_lds16(vptr + kt * 64, d);
    async_lds16(vptr + (size_t)32 * SDIM + kt * 64, d + 4096);
  };

  // QK^T(tile): for k-subtile s (32 k) and d-frag f (16 d):
  // A = K[kr = 32s+col][d = 16f + 8*half + e]  (chunk 2f+half, XOR row swz)
  auto qkt = [&](const u16* Kt, f32x16 (&sco)[2]) {
#pragma unroll
    for (int s = 0; s < 2; s++)
#pragma unroll
      for (int f = 0; f < 4; f++) {
        int kr = 32 * s + col;
        int phys = (2 * f + half) ^ (kr & 7);
        bf16x8 kf = *(const bf16x8*)&Kt[kr * 64 + phys * 8];
        sco[s] = MFMA32(kf, bq[f], sco[s]);
      }
  };

  float ps0 = 0.f, ps1 = 0.f, ps2 = 0.f, ps3 = 0.f;
  f32x16 oacc[2] = {};

  // softmax(t): 32 scores per lane (q=qi). Output: w[s][j] = bf16 pair of
  // (p[2j], p[2j+1]) — reg pairs are k-consecutive.
  auto smax = [&](int kt, f32x16 (&cur)[2], bool band, u32 (&w)[2][8]) {
#pragma unroll
    for (int s = 0; s < 2; s++) {
      float p[16];
#pragma unroll
      for (int r = 0; r < 16; r++) {
        float v = cur[s][r];
        if (band) {
          int j = kt * 64 + 32 * s + (r & 3) + 8 * (r >> 2) + 4 * half;
          if (j <= qi && j + 16 >= qi) v = -1.0e30f;
        }
        p[r] = __builtin_exp2f(v);
      }
#pragma unroll
      for (int r = 0; r < 16; r++) {
        if ((r & 3) == 0) ps0 += p[r];
        else if ((r & 3) == 1) ps1 += p[r];
        else if ((r & 3) == 2) ps2 += p[r];
        else ps3 += p[r];
      }
#pragma unroll
      for (int j = 0; j < 8; j++) {
        u32 wv;
        asm("v_cvt_pk_bf16_f32 %0, %1, %2" : "=v"(wv) : "v"(p[2 * j]), "v"(p[2 * j + 1]));
        w[s][j] = wv;
      }
    }
  };

  // PV(t): pa[ks] B-frag (k = 16*ks + 8*half + e) built by permlane32_swap:
  //   X' = {X.lo, Y.lo}, Y' = {X.hi, Y.hi}  with X = w[s][4b+j], Y = w[s][4b+2+j]
  // A = V^T[d = 32*dt + col][k]  read from VB (chunk 2*ks+half).
  auto pv = [&](const u16* Vt, u32 (&w)[2][8]) {
#pragma unroll
    for (int s = 0; s < 2; s++)
#pragma unroll
      for (int b2 = 0; b2 < 2; b2++) {
        u32 x0 = w[s][4 * b2 + 0], x1 = w[s][4 * b2 + 1];
        u32 y0 = w[s][4 * b2 + 2], y1 = w[s][4 * b2 + 3];
        asm("v_permlane32_swap_b32 %0, %1" : "+v"(x0), "+v"(y0));
        asm("v_permlane32_swap_b32 %0, %1" : "+v"(x1), "+v"(y1));
        uint4 pw;
        pw.x = x0; pw.y = x1; pw.z = y0; pw.w = y1;
        bf16x8 pa = __builtin_bit_cast(bf16x8, pw);
        int ks = 2 * s + b2;
#pragma unroll
        for (int dt = 0; dt < 2; dt++) {
          int vr = 32 * dt + col;
          int phys = (2 * ks + half) ^ (vr & 7);
          bf16x8 vf = *(const bf16x8*)&Vt[vr * 64 + phys * 8];
          oacc[dt] = MFMA32(vf, pa, oacc[dt]);
        }
      }
  };

  const int NT = SDIM / 64;  // 32

  auto body = [&](int kt, f32x16 (&cur)[2], f32x16 (&nxt)[2]) {
    __syncthreads();  // drains DMAs issued last iter: K(t+1), V(t+1)
    if (kt + 1 < NT) {
      nxt[0] = (f32x16){};
      nxt[1] = (f32x16){};
      qkt(KB[(kt + 1) & 1], nxt);  // MFMA, runs in background
    }
    if (kt + 2 < NT) {
      stageK(kt + 2, kt & 1);
      stageV(kt + 2, (unsigned)(kt + 2) % 3u);
    }
    u32 w[2][8];
    bool band = (kt * 64 <= qw0 + 31) && (kt * 64 + 63 >= qw0 - 16);
    smax(kt, cur, band, w);  // VALU, overlaps QK^T(t+1) MFMAs
    pv(VB[(unsigned)kt % 3u], w);
  };

  f32x16 scA[2] = {}, scB[2] = {};
  stageK(0, 0);
  stageV(0, 0);
  __syncthreads();
  qkt(KB[0], scA);
  stageK(1, 1);
  stageV(1, 1);

#pragma unroll 1
  for (int kt = 0; kt < NT; kt += 2) {
    body(kt, scA, scB);
    body(kt + 1, scB, scA);
  }

  // l(q) = psum(lane) + psum(lane^32)  (halves hold disjoint k subsets)
  float psum = (ps0 + ps1) + (ps2 + ps3);
  psum += __shfl_xor(psum, 32, 64);
  float linv = 1.0f / psum;

  // epilogue: lane holds O^T[d][q=qi]: d = 32*dt + 8*a + 4*half + (0..3)
  const int b = bh >> 4, h = bh & 15;
  u16* cbase = ctx + ((size_t)(b * SDIM + qi)) * EDIM + h * HD;
#pragma unroll
  for (int dt = 0; dt < 2; dt++)
#pragma unroll
    for (int a = 0; a < 4; a++) {
      float v0 = oacc[dt][4 * a + 0] * linv, v1 = oacc[dt][4 * a + 1] * linv;
      float v2 = oacc[dt][4 * a + 2] * linv, v3 = oacc[dt][4 * a + 3] * linv;
      u32 w0, w1;
      asm("v_cvt_pk_bf16_f32 %0, %1, %2" : "=v"(w0) : "v"(v0), "v"(v1));
      asm("v_cvt_pk_bf16_f32 %0, %1, %2" : "=v"(w1) : "v"(v2), "v"(v3));
      uint2 st;
      st.x = w0; st.y = w1;
      *(uint2*)(cbase + 32 * dt + 8 * a + 4 * half) = st;
    }
}

// ===================== GEMM2: output projection (128x128 tile, BK=64) ======
__global__ __launch_bounds__(256) void gemm_out_kernel(
    const u16* __restrict__ A, const u16* __restrict__ W,
    const float* __restrict__ bias, float* __restrict__ out) {
  __shared__ __align__(16) u16 As[128 * 64];
  __shared__ __align__(16) u16 Bs[128 * 64];
  const int m0 = blockIdx.x * 128, n0 = blockIdx.y * 128;
  const int t = threadIdx.x;
  const int l = t & 63;
  const int quad = l >> 4, col = l & 15;
  const int wid = t >> 6;
  const int mh = wid & 1, nh = wid >> 1;
  const int wofs = (t & 192) << 4;
  f32x4 acc[4][4] = {};
  const u16* Ab = A + (size_t)m0 * EDIM;
  const u16* Bb = W + (size_t)n0 * EDIM;
  char* AsB = (char*)As;
  char* BsB = (char*)Bs;

  for (int k0 = 0; k0 < EDIM; k0 += 64) {
    __syncthreads();
#pragma unroll
    for (int p = 0; p < 4; p++) {
      int idx = p * 256 + t;
      int row = idx >> 3;
      int gch = (idx & 7) ^ (row & 7);
      async_lds16(Ab + (size_t)row * EDIM + k0 + gch * 8, AsB + p * 4096 + wofs);
      async_lds16(Bb + (size_t)row * EDIM + k0 + gch * 8, BsB + p * 4096 + wofs);
    }
    __syncthreads();
#pragma unroll
    for (int kk = 0; kk < 2; kk++) {
      bf16x8 af[4], bfr[4];
#pragma unroll
      for (int i = 0; i < 4; i++) {
        int ra = 64 * mh + 16 * i + col;
        af[i] = *(const bf16x8*)&As[ra * 64 + (((kk * 4 + quad) ^ (ra & 7)) * 8)];
        int rb = 64 * nh + 16 * i + col;
        bfr[i] = *(const bf16x8*)&Bs[rb * 64 + (((kk * 4 + quad) ^ (rb & 7)) * 8)];
      }
#pragma unroll
      for (int i = 0; i < 4; i++)
#pragma unroll
        for (int j = 0; j < 4; j++)
          acc[i][j] = MFMA16(af[i], bfr[j], acc[i][j]);
    }
  }

#pragma unroll
  for (int i = 0; i < 4; i++)
#pragma unroll
    for (int j = 0; j < 4; j++)
#pragma unroll
      for (int r = 0; r < 4; r++) {
        int m = m0 + 64 * mh + 16 * i + quad * 4 + r;
        int n = n0 + 64 * nh + 16 * j + col;
        out[(size_t)m * EDIM + n] = acc[i][j][r] + bias[n];
      }
}

extern "C" void kernel_launch(void* const* d_in, const int* in_sizes, int n_in,
                              void* d_out, int out_size, void* d_ws,
                              size_t ws_size, hipStream_t stream) {
  const float* x = (const float*)d_in[0];
  const float* in_w = (const float*)d_in[2];
  const float* in_b = (const float*)d_in[3];
  const float* out_w = (const float*)d_in[4];
  const float* out_b = (const float*)d_in[5];
  float* out = (float*)d_out;

  char* ws = (char*)d_ws;
  u16* Xb  = (u16*)ws;                           // 8 MB (reused as ctx)
  u16* ctx = (u16*)ws;                           // alias of Xb
  u16* qb  = (u16*)(ws + (size_t)( 8 << 20));    // 8 MB (pre-scaled q)
  u16* kb  = (u16*)(ws + (size_t)(16 << 20));    // 8 MB
  u16* vtb = (u16*)(ws + (size_t)(24 << 20));    // 8 MB (transposed V)
  u16* Wib = (u16*)(ws + (size_t)(32 << 20));    // 6 MB
  u16* Wob = (u16*)(ws + (size_t)(38 << 20));    // 2 MB

  const int nX = MDIM * EDIM;
  const int nWi = 3 * EDIM * EDIM;
  const int nWo = EDIM * EDIM;
  cvt3_kernel<<<(nX + nWi + nWo) / 8 / 256, 256, 0, stream>>>(
      x, Xb, nX, in_w, Wib, nWi, out_w, Wob, nWo);

  gemm_qkv_kernel<<<dim3(MDIM / 128, 3 * EDIM / 128), 256, 0, stream>>>(
      Xb, Wib, in_b, qb, kb, vtb);
  attn_kernel<<<dim3(BDIM * HDIM, SDIM / 128), 256, 0, stream>>>(qb, kb, vtb, ctx);
  gemm_out_kernel<<<dim3(MDIM / 128, EDIM / 128), 256, 0, stream>>>(
      ctx, Wob, out_b, out);
}